// Round 9
// baseline (453.316 us; speedup 1.0000x reference)
//
#include <hip/hip_runtime.h>
#include <math.h>

// Problem constants (fixed by the reference)
#define BB 256
#define TT 512
#define DD 128
#define HH 128
#define GG 512   // 4*H
#define OO 64
#define NCH (TT / 4)   // 128 chunks of 4 timesteps

typedef _Float16 half8 __attribute__((ext_vector_type(8)));
typedef float    f32x4 __attribute__((ext_vector_type(4)));
typedef int      i32x4 __attribute__((ext_vector_type(4)));

// ---------------------------------------------------------------------------
// Fast activations (fp32; threshold 5.6e-3, plenty of headroom)
// ---------------------------------------------------------------------------
__device__ __forceinline__ float sigmoid_fast(float x) {
    return 1.0f / (1.0f + __expf(-x));
}
__device__ __forceinline__ float tanh_fast(float x) {
    float ax = fabsf(x);
    float e = __expf(2.0f * ax);
    float t = 1.0f - 2.0f / (e + 1.0f);
    return copysignf(t, x);
}

// ---------------------------------------------------------------------------
// Kernel 1 (fused): blocks [0,TT): xg; blocks [TT,TT+16): weight packing.
//
// xg[t][j][gt] = dot(x[255,t,:], W_ih[gt*128+j,:]) + b_ih + b_hh, PACKED
// per-hidden-index so the scan lane reads i,f,g,o as one 16-B vector.
// Only batch 255 matters: y.reshape(T,B,O)[-1] -> flat rows (b=255, t>=256);
// b=255's scan needs all t.
//
// wpack: W_hh f32 -> f16 per-lane MFMA B-fragments, 16 B contiguous:
//   wave w, n-tile nt(0..7), k-tile kt(0..3), lane l:
//   row = (nt>>1)*128 + (nt&1)*16 + w*32 + (l&15); off = kt*32 + (l>>4)*8
//   (fragment math identical to r3's numerically-verified scan).
// ---------------------------------------------------------------------------
__global__ __launch_bounds__(512) void xgpack_kernel(
    const float* __restrict__ x,
    const float* __restrict__ W_ih,
    const float* __restrict__ b_ih,
    const float* __restrict__ b_hh,
    const float* __restrict__ W_hh,
    float* __restrict__ xg,
    _Float16* __restrict__ Wp)
{
    if (blockIdx.x >= TT) {   // ---- weight-packing blocks ----
        const int g = (blockIdx.x - TT) * 512 + threadIdx.x;  // 0..8191
        const int fid = g >> 6, l = g & 63;
        const int w = fid >> 5, rem = fid & 31, nt = rem >> 2, kt = rem & 3;
        const int quad = l >> 4, col = l & 15;
        const int row = (nt >> 1) * 128 + (nt & 1) * 16 + w * 32 + col;
        const int off = kt * 32 + quad * 8;
        const float* s = W_hh + row * HH + off;
        _Float16* d = Wp + (size_t)g * 8;
#pragma unroll
        for (int i = 0; i < 8; i++) d[i] = (_Float16)s[i];
        return;
    }

    const int t = blockIdx.x;
    const int g = threadIdx.x;

    __shared__ __align__(16) float xs[DD];
    if (g < DD) xs[g] = x[(255 * TT + t) * DD + g];
    __syncthreads();

    const float4* __restrict__ wrow = (const float4*)(W_ih + g * DD);
    const float4* __restrict__ xv   = (const float4*)xs;

    float a0 = 0.f, a1 = 0.f, a2 = 0.f, a3 = 0.f;
#pragma unroll
    for (int i = 0; i < DD / 4; i += 4) {
        float4 w0 = wrow[i + 0], w1 = wrow[i + 1], w2 = wrow[i + 2], w3 = wrow[i + 3];
        float4 h0 = xv[i + 0],  h1 = xv[i + 1],  h2 = xv[i + 2],  h3 = xv[i + 3];
        a0 += w0.x * h0.x + w0.y * h0.y + w0.z * h0.z + w0.w * h0.w;
        a1 += w1.x * h1.x + w1.y * h1.y + w1.z * h1.z + w1.w * h1.w;
        a2 += w2.x * h2.x + w2.y * h2.y + w2.z * h2.z + w2.w * h2.w;
        a3 += w3.x * h3.x + w3.y * h3.y + w3.z * h3.z + w3.w * h3.w;
    }
    const float val = (a0 + a1) + (a2 + a3) + b_ih[g] + b_hh[g];
    xg[t * GG + (g & 127) * 4 + (g >> 7)] = val;   // packed [t][j][gate]
}

// ---------------------------------------------------------------------------
// Kernel 2: MFMA LSTM scan (batch 255). 1 block, 256 threads = 4 waves.
// r3's verified tile mapping: wave w owns 8 n-tiles (4 gates x 2 halves) of
// hidden slice [32w,32w+32); lane updates jsel = 32w + 16*sel + col.
//
// r9: the 32 MFMAs live in TWO asm volatile blocks whose B-operands are
// "a"-constrained (AGPR). The weights' ONLY use is an asm operand requiring
// AGPR -> the allocator must keep them resident (the r3-r8 failure was the
// allocator sinking weight loads into the loop; VGPR_Count 88-212 all < the
// 128 regs the fragments need). Hazard handling is manual:
//   entry s_nop 1  (VALU write -> MFMA read srcC)
//   exit  s_nop 7 x2 (MFMA write -> VALU read of C)
// xg is folded into the MFMA C-seed: only C reg 0 (row quad*4) is ever read,
// and element (row=4q, col) lives in lane 16q+col reg 0 = the reading lane,
// so CI[0] = xg_gate, CI[1..3] = 0 adds xg for free.
// ---------------------------------------------------------------------------
__global__
__attribute__((amdgpu_flat_work_group_size(256, 256), amdgpu_waves_per_eu(1, 1)))
void scan_kernel(
    const _Float16* __restrict__ Wp,
    const float* __restrict__ xgp,
    float* __restrict__ hs)
{
    const int tid  = threadIdx.x;
    const int lane = tid & 63;
    const int w    = tid >> 6;        // wave id 0..3
    const int col  = lane & 15;
    const int quad = lane >> 4;
    const int wbase = w * 32;
    const bool sel  = (lane >= 32);
    const int jsel  = wbase + (sel ? 16 : 0) + col; // hidden index this lane updates
    const int aoff  = quad * 8;

    __shared__ __align__(16) _Float16 h_lds[2][HH];          // 512 B
    __shared__ __align__(16) float xgc[2][4][HH][4];         // 16 KB
    __shared__ __align__(16) float hs_l[BB * HH];            // 128 KB

    // ---- B-fragments: contiguous 16-B loads from the packed buffer ----
#define BLOADP(nt, kt) \
    i32x4 B##nt##_##kt = *(const i32x4*)(Wp + (((w * 32 + (nt) * 4 + (kt)) * 64 + lane) * 8));
#define FOR_KT(X, nt) X(nt, 0) X(nt, 1) X(nt, 2) X(nt, 3)
#define FOR_NT(X) FOR_KT(X, 0) FOR_KT(X, 1) FOR_KT(X, 2) FOR_KT(X, 3) \
                  FOR_KT(X, 4) FOR_KT(X, 5) FOR_KT(X, 6) FOR_KT(X, 7)
    FOR_NT(BLOADP)

    if (tid < HH) h_lds[0][tid] = (_Float16)0.f;

    // preload xg chunk 0 into xgc[0] (8 KB = 512 f32x4; 2 per thread)
    {
        const f32x4* src = (const f32x4*)xgp;
        f32x4 a = src[2 * tid], b = src[2 * tid + 1];
        f32x4* dst = (f32x4*)&xgc[0][0][0][0];
        dst[2 * tid] = a; dst[2 * tid + 1] = b;
    }
    float c = 0.f;
    int p = 0;
    f32x4 CI0 = {0.f,0.f,0.f,0.f}, CI1 = {0.f,0.f,0.f,0.f};
    f32x4 CI2 = {0.f,0.f,0.f,0.f}, CI3 = {0.f,0.f,0.f,0.f};
    __syncthreads();

    f32x4 pf0, pf1;   // next-chunk prefetch registers

    for (int ch = 0; ch < NCH; ch++) {
        const int buf = ch & 1;
        if (ch + 1 < NCH) {   // issue next chunk's global loads early
            const f32x4* src = (const f32x4*)(xgp + (ch + 1) * 4 * GG);
            pf0 = src[2 * tid];
            pf1 = src[2 * tid + 1];
        }
#pragma unroll
        for (int k = 0; k < 4; k++) {
            const int t = ch * 4 + k;

            // A-fragments: h replicated over all 16 rows
            const _Float16* hl = h_lds[p];
            i32x4 A0 = *(const i32x4*)(hl + 0 * 32 + aoff);
            i32x4 A1 = *(const i32x4*)(hl + 1 * 32 + aoff);
            i32x4 A2 = *(const i32x4*)(hl + 2 * 32 + aoff);
            i32x4 A3 = *(const i32x4*)(hl + 3 * 32 + aoff);

            // packed gate biases -> MFMA C-seeds (reg 0 only; rows 1-3 unread)
            f32x4 xgv = *(const f32x4*)&xgc[buf][k][jsel][0];
            CI0[0] = xgv.x;  CI1[0] = xgv.y;
            CI2[0] = xgv.z;  CI3[0] = xgv.w;

            f32x4 C0, C1, C2, C3, C4, C5, C6, C7;

            // nt 0..3 (gates i, f), kt-outer for dependency spacing
            asm volatile(
                "s_nop 1\n\t"
                "v_mfma_f32_16x16x32_f16 %[c0], %[a0], %[b00], %[ci0]\n\t"
                "v_mfma_f32_16x16x32_f16 %[c1], %[a0], %[b10], %[ci0]\n\t"
                "v_mfma_f32_16x16x32_f16 %[c2], %[a0], %[b20], %[ci1]\n\t"
                "v_mfma_f32_16x16x32_f16 %[c3], %[a0], %[b30], %[ci1]\n\t"
                "v_mfma_f32_16x16x32_f16 %[c0], %[a1], %[b01], %[c0]\n\t"
                "v_mfma_f32_16x16x32_f16 %[c1], %[a1], %[b11], %[c1]\n\t"
                "v_mfma_f32_16x16x32_f16 %[c2], %[a1], %[b21], %[c2]\n\t"
                "v_mfma_f32_16x16x32_f16 %[c3], %[a1], %[b31], %[c3]\n\t"
                "v_mfma_f32_16x16x32_f16 %[c0], %[a2], %[b02], %[c0]\n\t"
                "v_mfma_f32_16x16x32_f16 %[c1], %[a2], %[b12], %[c1]\n\t"
                "v_mfma_f32_16x16x32_f16 %[c2], %[a2], %[b22], %[c2]\n\t"
                "v_mfma_f32_16x16x32_f16 %[c3], %[a2], %[b32], %[c3]\n\t"
                "v_mfma_f32_16x16x32_f16 %[c0], %[a3], %[b03], %[c0]\n\t"
                "v_mfma_f32_16x16x32_f16 %[c1], %[a3], %[b13], %[c1]\n\t"
                "v_mfma_f32_16x16x32_f16 %[c2], %[a3], %[b23], %[c2]\n\t"
                "v_mfma_f32_16x16x32_f16 %[c3], %[a3], %[b33], %[c3]\n\t"
                "s_nop 7\n\t"
                "s_nop 7"
                : [c0]"=&v"(C0), [c1]"=&v"(C1), [c2]"=&v"(C2), [c3]"=&v"(C3)
                : [a0]"v"(A0), [a1]"v"(A1), [a2]"v"(A2), [a3]"v"(A3),
                  [ci0]"v"(CI0), [ci1]"v"(CI1),
                  [b00]"a"(B0_0), [b01]"a"(B0_1), [b02]"a"(B0_2), [b03]"a"(B0_3),
                  [b10]"a"(B1_0), [b11]"a"(B1_1), [b12]"a"(B1_2), [b13]"a"(B1_3),
                  [b20]"a"(B2_0), [b21]"a"(B2_1), [b22]"a"(B2_2), [b23]"a"(B2_3),
                  [b30]"a"(B3_0), [b31]"a"(B3_1), [b32]"a"(B3_2), [b33]"a"(B3_3));

            // nt 4..7 (gates g, o)
            asm volatile(
                "s_nop 1\n\t"
                "v_mfma_f32_16x16x32_f16 %[c4], %[a0], %[b40], %[ci2]\n\t"
                "v_mfma_f32_16x16x32_f16 %[c5], %[a0], %[b50], %[ci2]\n\t"
                "v_mfma_f32_16x16x32_f16 %[c6], %[a0], %[b60], %[ci3]\n\t"
                "v_mfma_f32_16x16x32_f16 %[c7], %[a0], %[b70], %[ci3]\n\t"
                "v_mfma_f32_16x16x32_f16 %[c4], %[a1], %[b41], %[c4]\n\t"
                "v_mfma_f32_16x16x32_f16 %[c5], %[a1], %[b51], %[c5]\n\t"
                "v_mfma_f32_16x16x32_f16 %[c6], %[a1], %[b61], %[c6]\n\t"
                "v_mfma_f32_16x16x32_f16 %[c7], %[a1], %[b71], %[c7]\n\t"
                "v_mfma_f32_16x16x32_f16 %[c4], %[a2], %[b42], %[c4]\n\t"
                "v_mfma_f32_16x16x32_f16 %[c5], %[a2], %[b52], %[c5]\n\t"
                "v_mfma_f32_16x16x32_f16 %[c6], %[a2], %[b62], %[c6]\n\t"
                "v_mfma_f32_16x16x32_f16 %[c7], %[a2], %[b72], %[c7]\n\t"
                "v_mfma_f32_16x16x32_f16 %[c4], %[a3], %[b43], %[c4]\n\t"
                "v_mfma_f32_16x16x32_f16 %[c5], %[a3], %[b53], %[c5]\n\t"
                "v_mfma_f32_16x16x32_f16 %[c6], %[a3], %[b63], %[c6]\n\t"
                "v_mfma_f32_16x16x32_f16 %[c7], %[a3], %[b73], %[c7]\n\t"
                "s_nop 7\n\t"
                "s_nop 7"
                : [c4]"=&v"(C4), [c5]"=&v"(C5), [c6]"=&v"(C6), [c7]"=&v"(C7)
                : [a0]"v"(A0), [a1]"v"(A1), [a2]"v"(A2), [a3]"v"(A3),
                  [ci2]"v"(CI2), [ci3]"v"(CI3),
                  [b40]"a"(B4_0), [b41]"a"(B4_1), [b42]"a"(B4_2), [b43]"a"(B4_3),
                  [b50]"a"(B5_0), [b51]"a"(B5_1), [b52]"a"(B5_2), [b53]"a"(B5_3),
                  [b60]"a"(B6_0), [b61]"a"(B6_1), [b62]"a"(B6_2), [b63]"a"(B6_3),
                  [b70]"a"(B7_0), [b71]"a"(B7_1), [b72]"a"(B7_2), [b73]"a"(B7_3));

            // ---- epilogue: xg already folded in via CI seeds ----
            float pi = sel ? C1[0] : C0[0];
            float pf = sel ? C3[0] : C2[0];
            float pg = sel ? C5[0] : C4[0];
            float po = sel ? C7[0] : C6[0];

            float iv = sigmoid_fast(pi);
            float fv = sigmoid_fast(pf);
            float gv = tanh_fast(pg);
            float ov = sigmoid_fast(po);

            c = fv * c + iv * gv;
            float hval = ov * tanh_fast(c);

            // one writer pair per hidden index (quads 0 and 3)
            if (quad == 0 || quad == 3) {
                h_lds[1 - p][jsel] = (_Float16)hval;
                if (t >= TT - BB) hs_l[(t - (TT - BB)) * HH + jsel] = hval;
            }

            // stage the prefetched chunk into the other LDS buffer
            if (k == 3 && ch + 1 < NCH) {
                f32x4* dst = (f32x4*)&xgc[1 - buf][0][0][0];
                dst[2 * tid] = pf0;
                dst[2 * tid + 1] = pf1;
            }

            p ^= 1;
            __syncthreads();
        }
    }

    // dump hs (128 KB LDS -> global, coalesced)
    const f32x4* s = (const f32x4*)hs_l;
    f32x4* d = (f32x4*)hs;
#pragma unroll 4
    for (int i = tid; i < BB * HH / 4; i += 256) d[i] = s[i];
}

// ---------------------------------------------------------------------------
// Kernel 3: out[r,:] = W2 @ (W1 @ hs[r] + b1) + b2  (no activation in ref)
// ---------------------------------------------------------------------------
__global__ __launch_bounds__(128) void mlp_kernel(
    const float* __restrict__ hs,
    const float* __restrict__ W1,
    const float* __restrict__ b1,
    const float* __restrict__ W2,
    const float* __restrict__ b2,
    float* __restrict__ out)
{
    const int r = blockIdx.x;
    const int j = threadIdx.x;

    __shared__ __align__(16) float hsh[HH];
    __shared__ __align__(16) float z[HH];

    hsh[j] = hs[r * HH + j];
    __syncthreads();

    {
        const float4* __restrict__ wrow = (const float4*)(W1 + j * HH);
        const float4* __restrict__ hv   = (const float4*)hsh;
        float acc = b1[j];
#pragma unroll
        for (int i = 0; i < 32; i++) {
            float4 ww = wrow[i], h = hv[i];
            acc += ww.x * h.x + ww.y * h.y + ww.z * h.z + ww.w * h.w;
        }
        z[j] = acc;
    }
    __syncthreads();

    if (j < OO) {
        const float4* __restrict__ wrow = (const float4*)(W2 + j * HH);
        const float4* __restrict__ zv   = (const float4*)z;
        float acc = b2[j];
#pragma unroll
        for (int i = 0; i < 32; i++) {
            float4 ww = wrow[i], zz = zv[i];
            acc += ww.x * zz.x + ww.y * zz.y + ww.z * zz.z + ww.w * zz.w;
        }
        out[r * OO + j] = acc;
    }
}

// ---------------------------------------------------------------------------
// Launch. Inputs: 0:x 1:W_ih 2:W_hh 3:b_ih 4:b_hh 5:W1 6:b1 7:W2 8:b2
// ws: xg packed (1 MB) | hs (128 KB) | Wp packed f16 frags (128 KB)
// ---------------------------------------------------------------------------
extern "C" void kernel_launch(void* const* d_in, const int* in_sizes, int n_in,
                              void* d_out, int out_size, void* d_ws, size_t ws_size,
                              hipStream_t stream) {
    const float* x    = (const float*)d_in[0];
    const float* W_ih = (const float*)d_in[1];
    const float* W_hh = (const float*)d_in[2];
    const float* b_ih = (const float*)d_in[3];
    const float* b_hh = (const float*)d_in[4];
    const float* W1   = (const float*)d_in[5];
    const float* b1   = (const float*)d_in[6];
    const float* W2   = (const float*)d_in[7];
    const float* b2   = (const float*)d_in[8];
    float* out = (float*)d_out;

    float*    xg = (float*)d_ws;                 // T*4H   = 262144 f32 (packed)
    float*    hs = xg + TT * GG;                 // 256*H  =  32768 f32
    _Float16* Wp = (_Float16*)(hs + BB * HH);    // 4H*H   =  65536 f16 (packed frags)

    xgpack_kernel<<<TT + 16, 512, 0, stream>>>(x, W_ih, b_ih, b_hh, W_hh, xg, Wp);
    scan_kernel<<<1, 256, 0, stream>>>(Wp, xg, hs);
    mlp_kernel<<<BB, 128, 0, stream>>>(hs, W1, b1, W2, b2, out);
}

// Round 11
// 429.246 us; speedup vs baseline: 1.0561x; 1.0561x over previous
//
#include <hip/hip_runtime.h>
#include <math.h>

// Problem constants (fixed by the reference)
#define BB 256
#define TT 512
#define DD 128
#define HH 128
#define GG 512   // 4*H
#define OO 64
#define NCH (TT / 4)   // 128 chunks of 4 timesteps

typedef _Float16 half8 __attribute__((ext_vector_type(8)));
typedef float    f32x4 __attribute__((ext_vector_type(4)));

// ---------------------------------------------------------------------------
// Fast activations (fp32; threshold 5.6e-3, plenty of headroom)
// ---------------------------------------------------------------------------
__device__ __forceinline__ float sigmoid_fast(float x) {
    return 1.0f / (1.0f + __expf(-x));
}
__device__ __forceinline__ float tanh_fast(float x) {
    float ax = fabsf(x);
    float e = __expf(2.0f * ax);
    float t = 1.0f - 2.0f / (e + 1.0f);
    return copysignf(t, x);
}

// ---------------------------------------------------------------------------
// Kernel 1 (fused): blocks [0,TT): xg; blocks [TT,TT+16): weight packing.
//
// xg[t][j][gt]: input-gate contribution, PACKED per-hidden-index so the scan
// lane reads i,f,g,o as one 16-B vector. Only batch 255 matters:
// y.reshape(T,B,O)[-1] -> flat rows (b=255, t>=256); b=255's scan needs all t.
//
// wpack (8-wave layout): W_hh f32 -> f16 per-lane MFMA B-fragments:
//   wave w(0..7), gate gt(0..3), k-tile kt(0..3), lane l:
//   row = gt*128 + w*16 + (l&15); off = kt*32 + (l>>4)*8
//   dst = Wp[((w*16 + gt*4 + kt)*64 + l)*8 .. +8]
//   (identical index math to the r6/r7 numerically-verified 8-wave scan)
// ---------------------------------------------------------------------------
__global__ __launch_bounds__(512) void xgpack_kernel(
    const float* __restrict__ x,
    const float* __restrict__ W_ih,
    const float* __restrict__ b_ih,
    const float* __restrict__ b_hh,
    const float* __restrict__ W_hh,
    float* __restrict__ xg,
    _Float16* __restrict__ Wp)
{
    if (blockIdx.x >= TT) {   // ---- weight-packing blocks ----
        const int g = (blockIdx.x - TT) * 512 + threadIdx.x;  // 0..8191
        const int fid = g >> 6, l = g & 63;
        const int w = fid >> 4, gt = (fid >> 2) & 3, kt = fid & 3;
        const int quad = l >> 4, col = l & 15;
        const int row = gt * 128 + w * 16 + col;
        const int off = kt * 32 + quad * 8;
        const float* s = W_hh + row * HH + off;
        _Float16* d = Wp + (size_t)g * 8;
#pragma unroll
        for (int i = 0; i < 8; i++) d[i] = (_Float16)s[i];
        return;
    }

    const int t = blockIdx.x;
    const int g = threadIdx.x;

    __shared__ __align__(16) float xs[DD];
    if (g < DD) xs[g] = x[(255 * TT + t) * DD + g];
    __syncthreads();

    const float4* __restrict__ wrow = (const float4*)(W_ih + g * DD);
    const float4* __restrict__ xv   = (const float4*)xs;

    float a0 = 0.f, a1 = 0.f, a2 = 0.f, a3 = 0.f;
#pragma unroll
    for (int i = 0; i < DD / 4; i += 4) {
        float4 w0 = wrow[i + 0], w1 = wrow[i + 1], w2 = wrow[i + 2], w3 = wrow[i + 3];
        float4 h0 = xv[i + 0],  h1 = xv[i + 1],  h2 = xv[i + 2],  h3 = xv[i + 3];
        a0 += w0.x * h0.x + w0.y * h0.y + w0.z * h0.z + w0.w * h0.w;
        a1 += w1.x * h1.x + w1.y * h1.y + w1.z * h1.z + w1.w * h1.w;
        a2 += w2.x * h2.x + w2.y * h2.y + w2.z * h2.z + w2.w * h2.w;
        a3 += w3.x * h3.x + w3.y * h3.y + w3.z * h3.z + w3.w * h3.w;
    }
    const float val = (a0 + a1) + (a2 + a3) + b_ih[g] + b_hh[g];
    xg[t * GG + (g & 127) * 4 + (g >> 7)] = val;   // packed [t][j][gate]
}

// ---------------------------------------------------------------------------
// Kernel 2: MFMA LSTM scan (batch 255). 1 block, 512 threads = 8 waves
// (2 waves/SIMD so one wave's epilogue/LDS stalls hide under the other
// wave's MFMA issue -- m114 co-scheduling; the r8 4-wave version exposed
// the full serial chain on top of the MFMA pipe time).
//
// Wave w owns hidden slice [16w,16w+16) for ALL 4 gates (r6-verified map):
//   B-frag (gt,kt): gate row gt*128 + 16w + col, elems kt*32 + quad*8.
//   16 frags/wave = 64 VGPRs. A-frag: h replicated over all 16 rows.
//   Lane computes i,f,g,o for jsel = 16w+col directly from C0..C3 reg 0.
// xg folded into MFMA C-seed (r9-validated): lane seeds reg0 with xg[jsel];
// only reg0 (row 4*quad, col) is ever read and the seeding lane IS the
// reading lane.
// Weights: clean contiguous dwordx4 loads from the packed buffer -- cheap
// whether resident or re-loaded (r9 proved reloads are off-chain L2 hits;
// residency was never the bottleneck).
// ---------------------------------------------------------------------------
__global__
__attribute__((amdgpu_flat_work_group_size(512, 512), amdgpu_waves_per_eu(2, 2)))
void scan_kernel(
    const _Float16* __restrict__ Wp,
    const float* __restrict__ xgp,
    float* __restrict__ hs)
{
    const int tid  = threadIdx.x;
    const int lane = tid & 63;
    const int w    = tid >> 6;        // wave id 0..7
    const int col  = lane & 15;
    const int quad = lane >> 4;
    const int jsel = w * 16 + col;    // hidden index this lane computes
    const int aoff = quad * 8;

    __shared__ __align__(16) _Float16 h_lds[2][HH];          // 512 B
    __shared__ __align__(16) float xgc[2][4][HH][4];         // 16 KB
    __shared__ __align__(16) float hs_l[BB * HH];            // 128 KB

    // ---- B-fragments: contiguous 16-B loads from the packed buffer ----
#define BLOADP(gt, kt) \
    half8 B##gt##_##kt = *(const half8*)(Wp + (((w * 16 + (gt) * 4 + (kt)) * 64 + lane) * 8));
    BLOADP(0,0) BLOADP(0,1) BLOADP(0,2) BLOADP(0,3)
    BLOADP(1,0) BLOADP(1,1) BLOADP(1,2) BLOADP(1,3)
    BLOADP(2,0) BLOADP(2,1) BLOADP(2,2) BLOADP(2,3)
    BLOADP(3,0) BLOADP(3,1) BLOADP(3,2) BLOADP(3,3)

    if (tid < HH) h_lds[0][tid] = (_Float16)0.f;

    // preload xg chunk 0 into xgc[0] (8 KB = 512 f32x4; 1 per thread)
    {
        const f32x4* src = (const f32x4*)xgp;
        f32x4 a = src[tid];
        ((f32x4*)&xgc[0][0][0][0])[tid] = a;
    }
    float c = 0.f;
    int p = 0;
    __syncthreads();

    f32x4 pf;   // next-chunk prefetch register

    for (int ch = 0; ch < NCH; ch++) {
        const int buf = ch & 1;
        if (ch + 1 < NCH) {   // issue next chunk's global load early
            pf = ((const f32x4*)(xgp + (ch + 1) * 4 * GG))[tid];
        }
#pragma unroll
        for (int k = 0; k < 4; k++) {
            const int t = ch * 4 + k;

            // A-fragments: h replicated over all 16 rows
            const _Float16* hl = h_lds[p];
            half8 A0 = *(const half8*)(hl + 0 * 32 + aoff);
            half8 A1 = *(const half8*)(hl + 1 * 32 + aoff);
            half8 A2 = *(const half8*)(hl + 2 * 32 + aoff);
            half8 A3 = *(const half8*)(hl + 3 * 32 + aoff);

            // packed gate biases -> MFMA C-seeds (reg0 only; rows 1-3 unread)
            f32x4 xgv = *(const f32x4*)&xgc[buf][k][jsel][0];
            f32x4 C0 = {xgv.x, 0.f, 0.f, 0.f};
            f32x4 C1 = {xgv.y, 0.f, 0.f, 0.f};
            f32x4 C2 = {xgv.z, 0.f, 0.f, 0.f};
            f32x4 C3 = {xgv.w, 0.f, 0.f, 0.f};

            // 16 MFMAs: 4 gate-tiles x 4 k-tiles, kt-outer for dep spacing
#define MF(gt, kt) \
            C##gt = __builtin_amdgcn_mfma_f32_16x16x32_f16(A##kt, B##gt##_##kt, C##gt, 0, 0, 0);
            MF(0,0) MF(1,0) MF(2,0) MF(3,0)
            MF(0,1) MF(1,1) MF(2,1) MF(3,1)
            MF(0,2) MF(1,2) MF(2,2) MF(3,2)
            MF(0,3) MF(1,3) MF(2,3) MF(3,3)
#undef MF

            // ---- epilogue: xg already folded in via C seeds ----
            float iv = sigmoid_fast(C0[0]);
            float fv = sigmoid_fast(C1[0]);
            float gv = tanh_fast(C2[0]);
            float ov = sigmoid_fast(C3[0]);

            c = fv * c + iv * gv;
            float hval = ov * tanh_fast(c);

            // one writer per hidden index (quad 0; quads 1-3 duplicate)
            if (quad == 0) {
                h_lds[1 - p][jsel] = (_Float16)hval;
                if (t >= TT - BB) hs_l[(t - (TT - BB)) * HH + jsel] = hval;
            }

            // stage the prefetched chunk into the other LDS buffer
            if (k == 3 && ch + 1 < NCH) {
                ((f32x4*)&xgc[1 - buf][0][0][0])[tid] = pf;
            }

            p ^= 1;
            __syncthreads();
        }
    }

    // dump hs (128 KB LDS -> global, coalesced)
    const f32x4* s = (const f32x4*)hs_l;
    f32x4* d = (f32x4*)hs;
#pragma unroll 4
    for (int i = tid; i < BB * HH / 4; i += 512) d[i] = s[i];
}

// ---------------------------------------------------------------------------
// Kernel 3: out[r,:] = W2 @ (W1 @ hs[r] + b1) + b2  (no activation in ref)
// ---------------------------------------------------------------------------
__global__ __launch_bounds__(128) void mlp_kernel(
    const float* __restrict__ hs,
    const float* __restrict__ W1,
    const float* __restrict__ b1,
    const float* __restrict__ W2,
    const float* __restrict__ b2,
    float* __restrict__ out)
{
    const int r = blockIdx.x;
    const int j = threadIdx.x;

    __shared__ __align__(16) float hsh[HH];
    __shared__ __align__(16) float z[HH];

    hsh[j] = hs[r * HH + j];
    __syncthreads();

    {
        const float4* __restrict__ wrow = (const float4*)(W1 + j * HH);
        const float4* __restrict__ hv   = (const float4*)hsh;
        float acc = b1[j];
#pragma unroll
        for (int i = 0; i < 32; i++) {
            float4 ww = wrow[i], h = hv[i];
            acc += ww.x * h.x + ww.y * h.y + ww.z * h.z + ww.w * h.w;
        }
        z[j] = acc;
    }
    __syncthreads();

    if (j < OO) {
        const float4* __restrict__ wrow = (const float4*)(W2 + j * HH);
        const float4* __restrict__ zv   = (const float4*)z;
        float acc = b2[j];
#pragma unroll
        for (int i = 0; i < 32; i++) {
            float4 ww = wrow[i], zz = zv[i];
            acc += ww.x * zz.x + ww.y * zz.y + ww.z * zz.z + ww.w * zz.w;
        }
        out[r * OO + j] = acc;
    }
}

// ---------------------------------------------------------------------------
// Launch. Inputs: 0:x 1:W_ih 2:W_hh 3:b_ih 4:b_hh 5:W1 6:b1 7:W2 8:b2
// ws: xg packed (1 MB) | hs (128 KB) | Wp packed f16 frags (128 KB)
// ---------------------------------------------------------------------------
extern "C" void kernel_launch(void* const* d_in, const int* in_sizes, int n_in,
                              void* d_out, int out_size, void* d_ws, size_t ws_size,
                              hipStream_t stream) {
    const float* x    = (const float*)d_in[0];
    const float* W_ih = (const float*)d_in[1];
    const float* W_hh = (const float*)d_in[2];
    const float* b_ih = (const float*)d_in[3];
    const float* b_hh = (const float*)d_in[4];
    const float* W1   = (const float*)d_in[5];
    const float* b1   = (const float*)d_in[6];
    const float* W2   = (const float*)d_in[7];
    const float* b2   = (const float*)d_in[8];
    float* out = (float*)d_out;

    float*    xg = (float*)d_ws;                 // T*4H   = 262144 f32 (packed)
    float*    hs = xg + TT * GG;                 // 256*H  =  32768 f32
    _Float16* Wp = (_Float16*)(hs + BB * HH);    // 4H*H   =  65536 f16 (packed frags)

    xgpack_kernel<<<TT + 16, 512, 0, stream>>>(x, W_ih, b_ih, b_hh, W_hh, xg, Wp);
    scan_kernel<<<1, 512, 0, stream>>>(Wp, xg, hs);
    mlp_kernel<<<BB, 128, 0, stream>>>(hs, W1, b1, W2, b2, out);
}

// Round 13
// 385.536 us; speedup vs baseline: 1.1758x; 1.1134x over previous
//
#include <hip/hip_runtime.h>
#include <math.h>

// Problem constants (fixed by the reference)
#define BB 256
#define TT 512
#define DD 128
#define HH 128
#define GG 512   // 4*H
#define OO 64
#define NCH (TT / 4)   // 128 chunks of 4 timesteps

typedef _Float16 half8 __attribute__((ext_vector_type(8)));
typedef float    f32x4 __attribute__((ext_vector_type(4)));

// ---------------------------------------------------------------------------
// Fast activations (fp32; threshold 5.6e-3, plenty of headroom)
// ---------------------------------------------------------------------------
__device__ __forceinline__ float sigmoid_fast(float x) {
    return 1.0f / (1.0f + __expf(-x));
}
__device__ __forceinline__ float tanh_fast(float x) {
    float ax = fabsf(x);
    float e = __expf(2.0f * ax);
    float t = 1.0f - 2.0f / (e + 1.0f);
    return copysignf(t, x);
}

// ---------------------------------------------------------------------------
// Kernel 1 (fused): blocks [0,TT): xg; blocks [TT,TT+16): weight packing.
//
// xg[t][j][gt]: input-gate contribution, PACKED per-hidden-index so the scan
// lane reads i,f,g,o as one 16-B vector. Only batch 255 matters:
// y.reshape(T,B,O)[-1] -> flat rows (b=255, t>=256); b=255's scan needs all t.
//
// wpack (4-wave layout, r3/r8-verified fragment math):
//   wave w(0..3), n-tile nt(0..7), k-tile kt(0..3), lane l:
//   row = (nt>>1)*128 + (nt&1)*16 + w*32 + (l&15); off = kt*32 + (l>>4)*8
//   dst = Wp[((w*32 + nt*4 + kt)*64 + l)*8 .. +8]
// ---------------------------------------------------------------------------
__global__ __launch_bounds__(512) void xgpack_kernel(
    const float* __restrict__ x,
    const float* __restrict__ W_ih,
    const float* __restrict__ b_ih,
    const float* __restrict__ b_hh,
    const float* __restrict__ W_hh,
    float* __restrict__ xg,
    _Float16* __restrict__ Wp)
{
    if (blockIdx.x >= TT) {   // ---- weight-packing blocks ----
        const int g = (blockIdx.x - TT) * 512 + threadIdx.x;  // 0..8191
        const int fid = g >> 6, l = g & 63;
        const int w = fid >> 5, rem = fid & 31, nt = rem >> 2, kt = rem & 3;
        const int quad = l >> 4, col = l & 15;
        const int row = (nt >> 1) * 128 + (nt & 1) * 16 + w * 32 + col;
        const int off = kt * 32 + quad * 8;
        const float* s = W_hh + row * HH + off;
        _Float16* d = Wp + (size_t)g * 8;
#pragma unroll
        for (int i = 0; i < 8; i++) d[i] = (_Float16)s[i];
        return;
    }

    const int t = blockIdx.x;
    const int g = threadIdx.x;

    __shared__ __align__(16) float xs[DD];
    if (g < DD) xs[g] = x[(255 * TT + t) * DD + g];
    __syncthreads();

    const float4* __restrict__ wrow = (const float4*)(W_ih + g * DD);
    const float4* __restrict__ xv   = (const float4*)xs;

    float a0 = 0.f, a1 = 0.f, a2 = 0.f, a3 = 0.f;
#pragma unroll
    for (int i = 0; i < DD / 4; i += 4) {
        float4 w0 = wrow[i + 0], w1 = wrow[i + 1], w2 = wrow[i + 2], w3 = wrow[i + 3];
        float4 h0 = xv[i + 0],  h1 = xv[i + 1],  h2 = xv[i + 2],  h3 = xv[i + 3];
        a0 += w0.x * h0.x + w0.y * h0.y + w0.z * h0.z + w0.w * h0.w;
        a1 += w1.x * h1.x + w1.y * h1.y + w1.z * h1.z + w1.w * h1.w;
        a2 += w2.x * h2.x + w2.y * h2.y + w2.z * h2.z + w2.w * h2.w;
        a3 += w3.x * h3.x + w3.y * h3.y + w3.z * h3.z + w3.w * h3.w;
    }
    const float val = (a0 + a1) + (a2 + a3) + b_ih[g] + b_hh[g];
    xg[t * GG + (g & 127) * 4 + (g >> 7)] = val;   // packed [t][j][gate]
}

// ---------------------------------------------------------------------------
// Kernel 2: MFMA LSTM scan (batch 255). 1 block, 256 threads = 4 waves
// (r11 showed 8 waves doubles epilogue lanes + LDS-pipe traffic and loses).
// r3-verified tile map: wave w owns 8 n-tiles (4 gates x 2 halves) of hidden
// slice [32w,32w+32); lane updates jsel = 32w + 16*sel + col.
//
// r12/r13 change vs r8 (one variable): a ONE-TIME "+v" launder asm after the
// fragment loads. The values become opaque-defined -> the compiler cannot
// remat/sink the loads into the loop (the r8 storm: ~250 VALU instr/step of
// reload+addressing = ~560 cyc of the 1229-cyc step). Zero per-iteration
// cost, full in-loop scheduling freedom. waves_per_eu(1,1) guarantees the
// 512-reg budget so ~200 live regs don't spill.
// ---------------------------------------------------------------------------
__global__
__attribute__((amdgpu_flat_work_group_size(256, 256), amdgpu_waves_per_eu(1, 1)))
void scan_kernel(
    const _Float16* __restrict__ Wp,
    const float* __restrict__ xgp,
    float* __restrict__ hs)
{
    const int tid  = threadIdx.x;
    const int lane = tid & 63;
    const int w    = tid >> 6;        // wave id 0..3
    const int col  = lane & 15;
    const int quad = lane >> 4;
    const int wbase = w * 32;
    const bool sel  = (lane >= 32);
    const int jsel  = wbase + (sel ? 16 : 0) + col; // hidden index this lane updates
    const int aoff  = quad * 8;

    __shared__ __align__(16) _Float16 h_lds[2][HH];          // 512 B
    __shared__ __align__(16) float xgc[2][4][HH][4];         // 16 KB
    __shared__ __align__(16) float hs_l[BB * HH];            // 128 KB

    // ---- B-fragments: contiguous 16-B loads from the packed buffer ----
#define BLOADP(nt, kt) \
    half8 B##nt##_##kt = *(const half8*)(Wp + (((w * 32 + (nt) * 4 + (kt)) * 64 + lane) * 8));
#define FOR_KT(X, nt) X(nt, 0) X(nt, 1) X(nt, 2) X(nt, 3)
#define FOR_NT(X) FOR_KT(X, 0) FOR_KT(X, 1) FOR_KT(X, 2) FOR_KT(X, 3) \
                  FOR_KT(X, 4) FOR_KT(X, 5) FOR_KT(X, 6) FOR_KT(X, 7)
    FOR_NT(BLOADP)

    // ---- ONE-TIME launder: opaque-define the fragments (cannot be sunk) ----
    asm volatile("" : "+v"(B0_0), "+v"(B0_1), "+v"(B0_2), "+v"(B0_3),
                      "+v"(B1_0), "+v"(B1_1), "+v"(B1_2), "+v"(B1_3),
                      "+v"(B2_0), "+v"(B2_1), "+v"(B2_2), "+v"(B2_3),
                      "+v"(B3_0), "+v"(B3_1), "+v"(B3_2), "+v"(B3_3));
    asm volatile("" : "+v"(B4_0), "+v"(B4_1), "+v"(B4_2), "+v"(B4_3),
                      "+v"(B5_0), "+v"(B5_1), "+v"(B5_2), "+v"(B5_3),
                      "+v"(B6_0), "+v"(B6_1), "+v"(B6_2), "+v"(B6_3),
                      "+v"(B7_0), "+v"(B7_1), "+v"(B7_2), "+v"(B7_3));

    if (tid < HH) h_lds[0][tid] = (_Float16)0.f;

    // preload xg chunk 0 into xgc[0] (8 KB = 512 f32x4; 2 per thread)
    {
        const f32x4* src = (const f32x4*)xgp;
        f32x4 a = src[2 * tid], b = src[2 * tid + 1];
        f32x4* dst = (f32x4*)&xgc[0][0][0][0];
        dst[2 * tid] = a; dst[2 * tid + 1] = b;
    }
    float c = 0.f;
    int p = 0;
    __syncthreads();

    f32x4 pf0, pf1;   // next-chunk prefetch registers

    for (int ch = 0; ch < NCH; ch++) {
        const int buf = ch & 1;
        if (ch + 1 < NCH) {   // issue next chunk's global loads early
            const f32x4* src = (const f32x4*)(xgp + (ch + 1) * 4 * GG);
            pf0 = src[2 * tid];
            pf1 = src[2 * tid + 1];
        }
#pragma unroll
        for (int k = 0; k < 4; k++) {
            const int t = ch * 4 + k;

            // A-fragments: h replicated over all 16 rows
            const _Float16* hl = h_lds[p];
            half8 A0 = *(const half8*)(hl + 0 * 32 + aoff);
            half8 A1 = *(const half8*)(hl + 1 * 32 + aoff);
            half8 A2 = *(const half8*)(hl + 2 * 32 + aoff);
            half8 A3 = *(const half8*)(hl + 3 * 32 + aoff);

            // this step's packed gate biases (one ds_read_b128)
            f32x4 xgv = *(const f32x4*)&xgc[buf][k][jsel][0];

            f32x4 C0 = {0.f,0.f,0.f,0.f}, C1 = {0.f,0.f,0.f,0.f};
            f32x4 C2 = {0.f,0.f,0.f,0.f}, C3 = {0.f,0.f,0.f,0.f};
            f32x4 C4 = {0.f,0.f,0.f,0.f}, C5 = {0.f,0.f,0.f,0.f};
            f32x4 C6 = {0.f,0.f,0.f,0.f}, C7 = {0.f,0.f,0.f,0.f};
#define MF(nt, kt) \
            C##nt = __builtin_amdgcn_mfma_f32_16x16x32_f16(A##kt, B##nt##_##kt, C##nt, 0, 0, 0);
#define MF_ALLNT(kt) MF(0, kt) MF(1, kt) MF(2, kt) MF(3, kt) \
                     MF(4, kt) MF(5, kt) MF(6, kt) MF(7, kt)
            MF_ALLNT(0) MF_ALLNT(1) MF_ALLNT(2) MF_ALLNT(3)
#undef MF_ALLNT
#undef MF

            float pi = (sel ? C1[0] : C0[0]) + xgv.x;
            float pf = (sel ? C3[0] : C2[0]) + xgv.y;
            float pg = (sel ? C5[0] : C4[0]) + xgv.z;
            float po = (sel ? C7[0] : C6[0]) + xgv.w;

            float iv = sigmoid_fast(pi);
            float fv = sigmoid_fast(pf);
            float gv = tanh_fast(pg);
            float ov = sigmoid_fast(po);

            c = fv * c + iv * gv;
            float hval = ov * tanh_fast(c);

            // one writer pair per hidden index (quads 0 and 3)
            if (quad == 0 || quad == 3) {
                h_lds[1 - p][jsel] = (_Float16)hval;
                if (t >= TT - BB) hs_l[(t - (TT - BB)) * HH + jsel] = hval;
            }

            // stage the prefetched chunk into the other LDS buffer
            if (k == 3 && ch + 1 < NCH) {
                f32x4* dst = (f32x4*)&xgc[1 - buf][0][0][0];
                dst[2 * tid] = pf0;
                dst[2 * tid + 1] = pf1;
            }

            p ^= 1;
            __syncthreads();
        }
    }

    // dump hs (128 KB LDS -> global, coalesced)
    const f32x4* s = (const f32x4*)hs_l;
    f32x4* d = (f32x4*)hs;
#pragma unroll 4
    for (int i = tid; i < BB * HH / 4; i += 256) d[i] = s[i];
}

// ---------------------------------------------------------------------------
// Kernel 3: out[r,:] = W2 @ (W1 @ hs[r] + b1) + b2  (no activation in ref)
// ---------------------------------------------------------------------------
__global__ __launch_bounds__(128) void mlp_kernel(
    const float* __restrict__ hs,
    const float* __restrict__ W1,
    const float* __restrict__ b1,
    const float* __restrict__ W2,
    const float* __restrict__ b2,
    float* __restrict__ out)
{
    const int r = blockIdx.x;
    const int j = threadIdx.x;

    __shared__ __align__(16) float hsh[HH];
    __shared__ __align__(16) float z[HH];

    hsh[j] = hs[r * HH + j];
    __syncthreads();

    {
        const float4* __restrict__ wrow = (const float4*)(W1 + j * HH);
        const float4* __restrict__ hv   = (const float4*)hsh;
        float acc = b1[j];
#pragma unroll
        for (int i = 0; i < 32; i++) {
            float4 ww = wrow[i], h = hv[i];
            acc += ww.x * h.x + ww.y * h.y + ww.z * h.z + ww.w * h.w;
        }
        z[j] = acc;
    }
    __syncthreads();

    if (j < OO) {
        const float4* __restrict__ wrow = (const float4*)(W2 + j * HH);
        const float4* __restrict__ zv   = (const float4*)z;
        float acc = b2[j];
#pragma unroll
        for (int i = 0; i < 32; i++) {
            float4 ww = wrow[i], zz = zv[i];
            acc += ww.x * zz.x + ww.y * zz.y + ww.z * zz.z + ww.w * zz.w;
        }
        out[r * OO + j] = acc;
    }
}

// ---------------------------------------------------------------------------
// Launch. Inputs: 0:x 1:W_ih 2:W_hh 3:b_ih 4:b_hh 5:W1 6:b1 7:W2 8:b2
// ws: xg packed (1 MB) | hs (128 KB) | Wp packed f16 frags (128 KB)
// ---------------------------------------------------------------------------
extern "C" void kernel_launch(void* const* d_in, const int* in_sizes, int n_in,
                              void* d_out, int out_size, void* d_ws, size_t ws_size,
                              hipStream_t stream) {
    const float* x    = (const float*)d_in[0];
    const float* W_ih = (const float*)d_in[1];
    const float* W_hh = (const float*)d_in[2];
    const float* b_ih = (const float*)d_in[3];
    const float* b_hh = (const float*)d_in[4];
    const float* W1   = (const float*)d_in[5];
    const float* b1   = (const float*)d_in[6];
    const float* W2   = (const float*)d_in[7];
    const float* b2   = (const float*)d_in[8];
    float* out = (float*)d_out;

    float*    xg = (float*)d_ws;                 // T*4H   = 262144 f32 (packed)
    float*    hs = xg + TT * GG;                 // 256*H  =  32768 f32
    _Float16* Wp = (_Float16*)(hs + BB * HH);    // 4H*H   =  65536 f16 (packed frags)

    xgpack_kernel<<<TT + 16, 512, 0, stream>>>(x, W_ih, b_ih, b_hh, W_hh, xg, Wp);
    scan_kernel<<<1, 256, 0, stream>>>(Wp, xg, hs);
    mlp_kernel<<<BB, 128, 0, stream>>>(hs, W1, b1, W2, b2, out);
}